// Round 1
// baseline (1000.585 us; speedup 1.0000x reference)
//
#include <hip/hip_runtime.h>

namespace {
constexpr int Bn  = 8;
constexpr int Nn  = 4096;
constexpr int KKn = 20;
constexpr int C1n = 64;
constexpr int C2n = 128;
constexpr int C3n = 256;
constexpr float EPSc = 1e-5f;
constexpr float INV_CNT1 = 1.0f / (8.0f * 4096.0f * 20.0f);  // B*N*k
constexpr float INV_CNT3 = 1.0f / (8.0f * 4096.0f);          // B*N
}

#define DEVI __device__ __forceinline__

// ---------------------------------------------------------------------------
// K0: zero the stat accumulators (ws is poisoned 0xAA before every call)
// layout in stats buffer (floats): s1[64] q1[64] s2[128] q2[128] s3[256] q3[256]
__global__ void k_zero(float* __restrict__ stats) {
    const int i = blockIdx.x * 256 + threadIdx.x;
    if (i < 896) stats[i] = 0.0f;
}

// ---------------------------------------------------------------------------
// K1: kNN (top-20 by squared distance, tie-break by smaller index) fused with
// conv1 BN statistics (channel = lane).
__global__ __launch_bounds__(256) void k_knn(const float* __restrict__ x,
                                             const float* __restrict__ W1,
                                             int* __restrict__ idxout,
                                             float* __restrict__ stats) {
    __shared__ float xs[Nn], ys[Nn], zs[Nn];
    __shared__ float red[4][64];
    const int b = blockIdx.y;
    const float* xb = x + b * 3 * Nn;
    for (int t = threadIdx.x; t < Nn; t += 256) {
        xs[t] = xb[t]; ys[t] = xb[Nn + t]; zs[t] = xb[2 * Nn + t];
    }
    const int lane = threadIdx.x & 63;
    const int wave = threadIdx.x >> 6;
    // W1 row for this lane's channel
    const float w0 = W1[lane * 6 + 0], w1 = W1[lane * 6 + 1], w2 = W1[lane * 6 + 2];
    const float w3 = W1[lane * 6 + 3], w4 = W1[lane * 6 + 4], w5 = W1[lane * 6 + 5];
    float ss = 0.0f, sq = 0.0f;
    __syncthreads();

    for (int rr = 0; rr < 16; ++rr) {
        const int i = blockIdx.x * 64 + wave * 16 + rr;
        const float px = xs[i], py = ys[i], pz = zs[i];
        const float t2 = fmaf(w3, px, fmaf(w4, py, w5 * pz));
        // per-lane top-3 of its 64 strided candidates, (d, j) lexicographic
        float m0 = 3.0e38f, m1 = 3.0e38f, m2 = 3.0e38f;
        int   j0 = -1, j1 = -1, j2 = -1;
        #pragma unroll 8
        for (int t = 0; t < 64; ++t) {
            const int j = t * 64 + lane;
            const float dx = px - xs[j], dy = py - ys[j], dz = pz - zs[j];
            const float d = fmaf(dx, dx, fmaf(dy, dy, dz * dz));
            if (d < m2) {
                if (d < m1) {
                    m2 = m1; j2 = j1;
                    if (d < m0) { m1 = m0; j1 = j0; m0 = d; j0 = j; }
                    else        { m1 = d;  j1 = j; }
                } else { m2 = d; j2 = j; }
            }
        }
        int nv = 3;
        const int outbase = (b * Nn + i) * KKn;
        for (int s = 0; s < KKn; ++s) {
            float bd = (nv > 0) ? m0 : 3.0e38f;
            int   bj = (nv > 0) ? j0 : -1;
            #pragma unroll
            for (int off = 32; off; off >>= 1) {
                const float od = __shfl_xor(bd, off);
                const int   oj = __shfl_xor(bj, off);
                if (od < bd || (od == bd && (unsigned)oj < (unsigned)bj)) { bd = od; bj = oj; }
            }
            if (lane == 0) idxout[outbase + s] = bj;
            // fused conv1 stats (pre-BN h1 for this (row, k), channel = lane)
            {
                const float dx = xs[bj] - px, dy = ys[bj] - py, dz = zs[bj] - pz;
                const float h = fmaf(w0, dx, fmaf(w1, dy, fmaf(w2, dz, t2)));
                ss += h; sq = fmaf(h, h, sq);
            }
            if (nv > 0 && j0 == bj) {   // we won: pop
                m0 = m1; j0 = j1; m1 = m2; j1 = j2; --nv;
                if (nv == 0 && s < KKn - 1) {
                    // rare rescan: rebuild top-3 among keys > (bd, bj)
                    m0 = m1 = m2 = 3.0e38f; j0 = j1 = j2 = -1;
                    #pragma unroll 1
                    for (int t = 0; t < 64; ++t) {
                        const int j = t * 64 + lane;
                        const float dx2 = px - xs[j], dy2 = py - ys[j], dz2 = pz - zs[j];
                        const float d = fmaf(dx2, dx2, fmaf(dy2, dy2, dz2 * dz2));
                        const bool ok = (d > bd) || (d == bd && j > bj);
                        if (ok && d < m2) {
                            if (d < m1) {
                                m2 = m1; j2 = j1;
                                if (d < m0) { m1 = m0; j1 = j0; m0 = d; j0 = j; }
                                else        { m1 = d;  j1 = j; }
                            } else { m2 = d; j2 = j; }
                        }
                    }
                    nv = 3;
                }
            }
        }
    }
    // block reduce + atomic for stats1
    red[wave][lane] = ss;
    __syncthreads();
    if (wave == 0) {
        const float t = red[0][lane] + red[1][lane] + red[2][lane] + red[3][lane];
        atomicAdd(&stats[lane], t);
    }
    __syncthreads();
    red[wave][lane] = sq;
    __syncthreads();
    if (wave == 0) {
        const float t = red[0][lane] + red[1][lane] + red[2][lane] + red[3][lane];
        atomicAdd(&stats[64 + lane], t);
    }
}

// ---------------------------------------------------------------------------
// shared phase-1: recompute h1_hat (normalized+relu conv1) for 8 points into
// LDS [160][64]; optionally attn-pool into cat[:, 0:64].
template <bool POOL>
DEVI void conv1_phase1(const float* __restrict__ x, const int* __restrict__ idx,
                       const float* __restrict__ W1, const float* __restrict__ g1,
                       const float* __restrict__ b1, const float* __restrict__ stats,
                       float* __restrict__ cat, int b, int n0, int tid,
                       float (*hhat)[64]) {
    const int o = tid & 63;
    const int wave = tid >> 6;
    float a1, be1;
    {
        const float mu  = stats[o] * INV_CNT1;
        const float var = stats[64 + o] * INV_CNT1 - mu * mu;
        const float rs  = rsqrtf(var + EPSc);
        a1 = rs * g1[o];
        be1 = fmaf(-mu, a1, b1[o]);
    }
    float w1r[6];
    #pragma unroll
    for (int c = 0; c < 6; ++c) w1r[c] = W1[o * 6 + c];
    const float* xb = x + b * 3 * Nn;
    #pragma unroll
    for (int pp = 0; pp < 2; ++pp) {
        const int p = wave * 2 + pp;
        const int n = n0 + p;
        const float cx = xb[n], cy = xb[Nn + n], cz = xb[2 * Nn + n];
        const float t2 = fmaf(w1r[3], cx, fmaf(w1r[4], cy, w1r[5] * cz));
        float hk[KKn];
        #pragma unroll
        for (int kk = 0; kk < KKn; ++kk) {
            const int j = idx[(b * Nn + n) * KKn + kk];
            const float dx = xb[j] - cx, dy = xb[Nn + j] - cy, dz = xb[2 * Nn + j] - cz;
            float h = fmaf(w1r[0], dx, fmaf(w1r[1], dy, fmaf(w1r[2], dz, t2)));
            h = fmaxf(fmaf(h, a1, be1), 0.0f);
            hk[kk] = h;
            hhat[p * KKn + kk][o] = h;
        }
        if (POOL) {
            float mx = hk[0];
            #pragma unroll
            for (int kk = 1; kk < KKn; ++kk) mx = fmaxf(mx, hk[kk]);
            float se = 0.0f, sw = 0.0f;
            #pragma unroll
            for (int kk = 0; kk < KKn; ++kk) {
                const float e = __expf(hk[kk] - mx);
                se += e;
                sw = fmaf(hk[kk], e, sw);
            }
            cat[(b * Nn + n) * 192 + o] = sw / se;
        }
    }
}

// ---------------------------------------------------------------------------
// K2: phase1 (+x1 pool) then conv2 pre-BN statistics (register-tiled 4ch x 4pair)
__global__ __launch_bounds__(256) void k_conv1(const float* __restrict__ x,
        const int* __restrict__ idx,
        const float* __restrict__ W1, const float* __restrict__ g1, const float* __restrict__ b1,
        const float* __restrict__ W2,
        const float* __restrict__ stats,     // s1 at [0], q1 at [64]
        float* __restrict__ stats2,          // s2 at [0], q2 at [128]
        float* __restrict__ cat) {
    __shared__ float hhat[160][64];
    __shared__ float w2s[C2n][68];           // pad 68: float4-aligned + conflict-free
    __shared__ float red[8][128];
    const int tid = threadIdx.x;
    const int b  = blockIdx.x >> 9;
    const int n0 = (blockIdx.x & 511) * 8;
    for (int t = tid; t < C2n * C1n; t += 256) w2s[t >> 6][t & 63] = W2[t];
    conv1_phase1<true>(x, idx, W1, g1, b1, stats, cat, b, n0, tid, hhat);
    __syncthreads();

    const int q = tid & 31;
    const int slot = tid >> 5;               // 0..7
    float s2[4] = {0, 0, 0, 0}, q2a[4] = {0, 0, 0, 0};
    for (int it = 0; it < 5; ++it) {
        const int pbase = (it * 8 + slot) * 4;
        float acc[4][4] = {};
        for (int oc = 0; oc < 16; ++oc) {
            float4 h[4];
            #pragma unroll
            for (int r = 0; r < 4; ++r)
                h[r] = *reinterpret_cast<const float4*>(&hhat[pbase + r][oc * 4]);
            #pragma unroll
            for (int m = 0; m < 4; ++m) {
                const float4 w = *reinterpret_cast<const float4*>(&w2s[q + 32 * m][oc * 4]);
                #pragma unroll
                for (int r = 0; r < 4; ++r) {
                    acc[m][r] = fmaf(w.x, h[r].x, acc[m][r]);
                    acc[m][r] = fmaf(w.y, h[r].y, acc[m][r]);
                    acc[m][r] = fmaf(w.z, h[r].z, acc[m][r]);
                    acc[m][r] = fmaf(w.w, h[r].w, acc[m][r]);
                }
            }
        }
        #pragma unroll
        for (int m = 0; m < 4; ++m) {
            #pragma unroll
            for (int r = 0; r < 4; ++r) {
                const float v = acc[m][r];
                s2[m] += v;
                q2a[m] = fmaf(v, v, q2a[m]);
            }
        }
    }
    #pragma unroll
    for (int m = 0; m < 4; ++m) red[slot][q + 32 * m] = s2[m];
    __syncthreads();
    if (tid < 128) {
        float t = 0.0f;
        #pragma unroll
        for (int s = 0; s < 8; ++s) t += red[s][tid];
        atomicAdd(&stats2[tid], t);
    }
    __syncthreads();
    #pragma unroll
    for (int m = 0; m < 4; ++m) red[slot][q + 32 * m] = q2a[m];
    __syncthreads();
    if (tid < 128) {
        float t = 0.0f;
        #pragma unroll
        for (int s = 0; s < 8; ++s) t += red[s][tid];
        atomicAdd(&stats2[128 + tid], t);
    }
}

// ---------------------------------------------------------------------------
// K3: phase1 again, then conv2 + BN + relu + attn-pool -> cat[:, 64:192]
__global__ __launch_bounds__(256) void k_conv2(const float* __restrict__ x,
        const int* __restrict__ idx,
        const float* __restrict__ W1, const float* __restrict__ g1, const float* __restrict__ b1,
        const float* __restrict__ W2, const float* __restrict__ g2, const float* __restrict__ b2,
        const float* __restrict__ stats,     // s1/q1
        const float* __restrict__ stats2,    // s2 at [0], q2 at [128]
        float* __restrict__ cat) {
    __shared__ float hhat[160][64];
    __shared__ float w2s[C2n][68];
    const int tid = threadIdx.x;
    const int b  = blockIdx.x >> 9;
    const int n0 = (blockIdx.x & 511) * 8;
    for (int t = tid; t < C2n * C1n; t += 256) w2s[t >> 6][t & 63] = W2[t];
    conv1_phase1<false>(x, idx, W1, g1, b1, stats, cat, b, n0, tid, hhat);
    __syncthreads();

    const int q = tid & 31;
    const int p = tid >> 5;                  // local point 0..7
    const int n = n0 + p;
    float a2[4], be2[4];
    #pragma unroll
    for (int m = 0; m < 4; ++m) {
        const int ch = q + 32 * m;
        const float mu  = stats2[ch] * INV_CNT1;
        const float var = stats2[128 + ch] * INV_CNT1 - mu * mu;
        const float rs  = rsqrtf(var + EPSc);
        a2[m] = rs * g2[ch];
        be2[m] = fmaf(-mu, a2[m], b2[ch]);
    }
    float acc[4][KKn] = {};
    for (int oc = 0; oc < 16; ++oc) {
        float4 w[4];
        #pragma unroll
        for (int m = 0; m < 4; ++m)
            w[m] = *reinterpret_cast<const float4*>(&w2s[q + 32 * m][oc * 4]);
        #pragma unroll
        for (int kk = 0; kk < KKn; ++kk) {
            const float4 h = *reinterpret_cast<const float4*>(&hhat[p * KKn + kk][oc * 4]);
            #pragma unroll
            for (int m = 0; m < 4; ++m) {
                acc[m][kk] = fmaf(w[m].x, h.x, acc[m][kk]);
                acc[m][kk] = fmaf(w[m].y, h.y, acc[m][kk]);
                acc[m][kk] = fmaf(w[m].z, h.z, acc[m][kk]);
                acc[m][kk] = fmaf(w[m].w, h.w, acc[m][kk]);
            }
        }
    }
    #pragma unroll
    for (int m = 0; m < 4; ++m) {
        float v[KKn];
        float mx = 0.0f;
        #pragma unroll
        for (int kk = 0; kk < KKn; ++kk) {
            v[kk] = fmaxf(fmaf(acc[m][kk], a2[m], be2[m]), 0.0f);
            mx = fmaxf(mx, v[kk]);
        }
        float se = 0.0f, sw = 0.0f;
        #pragma unroll
        for (int kk = 0; kk < KKn; ++kk) {
            const float e = __expf(v[kk] - mx);
            se += e;
            sw = fmaf(v[kk], e, sw);
        }
        cat[(b * Nn + n) * 192 + 64 + q + 32 * m] = sw / se;
    }
}

// ---------------------------------------------------------------------------
// K4: FC 256<-192 over cat, write pre-BN to d_out, accumulate stats3
__global__ __launch_bounds__(256) void k_fc(const float* __restrict__ cat,
        const float* __restrict__ W3,
        float* __restrict__ stats3, float* __restrict__ out) {
    __shared__ float w3s[C3n][52];           // 48-col chunk, stride 52 (13*16B rows)
    __shared__ float ctf[32 * 192];
    const int tid = threadIdx.x;
    const int b  = blockIdx.x >> 7;          // 128 blocks per batch
    const int n0 = (blockIdx.x & 127) * 32;
    const int base = (b * Nn + n0) * 192;
    for (int t = tid; t < 32 * 192; t += 256) ctf[t] = cat[base + t];
    const int o3a = tid & 127;               // this thread: channels o3a and o3a+128
    const int ph  = tid >> 7;                // point half 0/1
    float acc[2][16] = {};
    for (int ch = 0; ch < 4; ++ch) {
        __syncthreads();
        for (int t = tid; t < 256 * 48; t += 256) {
            const int row = t / 48, col = t - row * 48;
            w3s[row][col] = W3[row * 192 + ch * 48 + col];
        }
        __syncthreads();
        for (int c4 = 0; c4 < 12; ++c4) {
            const int c = c4 * 4;
            const float4 wA = *reinterpret_cast<const float4*>(&w3s[o3a][c]);
            const float4 wB = *reinterpret_cast<const float4*>(&w3s[o3a + 128][c]);
            #pragma unroll
            for (int p = 0; p < 16; ++p) {
                const int gp = ph * 16 + p;
                const float4 h = *reinterpret_cast<const float4*>(&ctf[gp * 192 + ch * 48 + c]);
                acc[0][p] = fmaf(wA.x, h.x, acc[0][p]);
                acc[0][p] = fmaf(wA.y, h.y, acc[0][p]);
                acc[0][p] = fmaf(wA.z, h.z, acc[0][p]);
                acc[0][p] = fmaf(wA.w, h.w, acc[0][p]);
                acc[1][p] = fmaf(wB.x, h.x, acc[1][p]);
                acc[1][p] = fmaf(wB.y, h.y, acc[1][p]);
                acc[1][p] = fmaf(wB.z, h.z, acc[1][p]);
                acc[1][p] = fmaf(wB.w, h.w, acc[1][p]);
            }
        }
    }
    #pragma unroll
    for (int half = 0; half < 2; ++half) {
        const int o3 = o3a + half * 128;
        float s = 0.0f, qq = 0.0f;
        #pragma unroll
        for (int p = 0; p < 16; ++p) {
            const float v = acc[half][p];
            s += v;
            qq = fmaf(v, v, qq);
            out[(b * C3n + o3) * Nn + n0 + ph * 16 + p] = v;
        }
        atomicAdd(&stats3[o3], s);
        atomicAdd(&stats3[C3n + o3], qq);
    }
}

// ---------------------------------------------------------------------------
// K5: in-place BN+relu on d_out
__global__ __launch_bounds__(256) void k_bnout(const float* __restrict__ stats3,
        const float* __restrict__ g3, const float* __restrict__ b3,
        float* __restrict__ out) {
    __shared__ float al[C3n], be[C3n];
    const int tid = threadIdx.x;
    {
        const int ch = tid;
        const float mu  = stats3[ch] * INV_CNT3;
        const float var = stats3[C3n + ch] * INV_CNT3 - mu * mu;
        const float rs  = rsqrtf(var + EPSc);
        al[ch] = rs * g3[ch];
        be[ch] = fmaf(-mu, al[ch], b3[ch]);
    }
    __syncthreads();
    const int total = Bn * C3n * Nn / 4;     // float4 count
    float4* o4 = reinterpret_cast<float4*>(out);
    for (int i = blockIdx.x * 256 + tid; i < total; i += gridDim.x * 256) {
        const int ch = (i >> 10) & 255;      // Nn/4 = 1024 float4 per (b, ch) row
        float4 v = o4[i];
        const float a = al[ch], bb = be[ch];
        v.x = fmaxf(fmaf(v.x, a, bb), 0.0f);
        v.y = fmaxf(fmaf(v.y, a, bb), 0.0f);
        v.z = fmaxf(fmaf(v.z, a, bb), 0.0f);
        v.w = fmaxf(fmaf(v.w, a, bb), 0.0f);
        o4[i] = v;
    }
}

// ---------------------------------------------------------------------------
extern "C" void kernel_launch(void* const* d_in, const int* in_sizes, int n_in,
                              void* d_out, int out_size, void* d_ws, size_t ws_size,
                              hipStream_t stream) {
    const float* x  = (const float*)d_in[0];
    const float* W1 = (const float*)d_in[1];
    const float* g1 = (const float*)d_in[2];
    const float* b1 = (const float*)d_in[3];
    const float* W2 = (const float*)d_in[4];
    const float* g2 = (const float*)d_in[5];
    const float* b2 = (const float*)d_in[6];
    const float* W3 = (const float*)d_in[7];
    const float* g3 = (const float*)d_in[8];
    const float* b3 = (const float*)d_in[9];
    float* out = (float*)d_out;

    int*   idx   = (int*)d_ws;
    float* stats = (float*)d_ws + (size_t)Bn * Nn * KKn;     // 896 floats used
    float* cat   = stats + 1024;                              // [B][N][192]

    k_zero<<<4, 256, 0, stream>>>(stats);
    k_knn<<<dim3(Nn / 64, Bn), 256, 0, stream>>>(x, W1, idx, stats);
    k_conv1<<<Bn * Nn / 8, 256, 0, stream>>>(x, idx, W1, g1, b1, W2,
                                             stats, stats + 128, cat);
    k_conv2<<<Bn * Nn / 8, 256, 0, stream>>>(x, idx, W1, g1, b1, W2, g2, b2,
                                             stats, stats + 128, cat);
    k_fc<<<Bn * Nn / 32, 256, 0, stream>>>(cat, W3, stats + 384, out);
    k_bnout<<<2048, 256, 0, stream>>>(stats + 384, g3, b3, out);
}